// Round 3
// baseline (722.750 us; speedup 1.0000x reference)
//
#include <hip/hip_runtime.h>
#include <math.h>

#define DIM 96
#define HW_ (DIM*DIM)          // 9216
#define N3 (DIM*DIM*DIM)       // 884736
#define TPB 256

template<int K> struct CW { float w[K]; };

// Generic 1-D conv along an axis with compile-time STRIDE (1=W, 96=H, 9216=D).
// Zero padding implemented by skipping out-of-range taps. Works for multi-field
// contiguous arrays (total = nfields*N3) because taps never cross field bounds.
template<int R, int STRIDE>
__global__ void conv1d(const float* __restrict__ in, float* __restrict__ out,
                       int total, CW<2*R+1> wt) {
  int idx = blockIdx.x * TPB + threadIdx.x;
  if (idx >= total) return;
  int c = (idx / STRIDE) % DIM;
  float s = 0.f;
#pragma unroll
  for (int j = -R; j <= R; ++j) {
    int cc = c + j;
    if (0 <= cc && cc < DIM) s += wt.w[j + R] * in[idx + j * STRIDE];
  }
  out[idx] = s;
}

// Same, but two outputs with two weight sets from one read of the input.
template<int R, int STRIDE>
__global__ void conv1d_dual(const float* __restrict__ in,
                            float* __restrict__ outA, float* __restrict__ outB,
                            int total, CW<2*R+1> wa, CW<2*R+1> wb) {
  int idx = blockIdx.x * TPB + threadIdx.x;
  if (idx >= total) return;
  int c = (idx / STRIDE) % DIM;
  float sa = 0.f, sb = 0.f;
#pragma unroll
  for (int j = -R; j <= R; ++j) {
    int cc = c + j;
    if (0 <= cc && cc < DIM) {
      float v = in[idx + j * STRIDE];
      sa += wa.w[j + R] * v;
      sb += wb.w[j + R] * v;
    }
  }
  outA[idx] = sa;
  outB[idx] = sb;
}

// Products of gradients + 13-tap conv along W, producing 6 comps at stride N3.
__global__ void prod_convW(const float* __restrict__ gx, const float* __restrict__ gy,
                           const float* __restrict__ gz, float* __restrict__ out,
                           CW<13> wt) {
  int idx = blockIdx.x * TPB + threadIdx.x;
  if (idx >= N3) return;
  int x = idx % DIM;
  float a0=0.f,a1=0.f,a2=0.f,a3=0.f,a4=0.f,a5=0.f;
#pragma unroll
  for (int j = -6; j <= 6; ++j) {
    int xx = x + j;
    if (xx < 0 || xx >= DIM) continue;
    float w = wt.w[j + 6];
    float a = gx[idx + j], b = gy[idx + j], c = gz[idx + j];
    a0 += w * a * a;  a1 += w * b * b;  a2 += w * c * c;
    a3 += w * a * b;  a4 += w * a * c;  a5 += w * b * c;
  }
  out[0*N3+idx]=a0; out[1*N3+idx]=a1; out[2*N3+idx]=a2;
  out[3*N3+idx]=a3; out[4*N3+idx]=a4; out[5*N3+idx]=a5;
}

// One cyclic-Jacobi rotation for pair (P,Q), remaining index RR.
template<int P, int Q, int RR>
__device__ inline void jrot(float a[3][3], float V[3][3]) {
  float apq = a[P][Q];
  if (apq != 0.f) {
    float app = a[P][P], aqq = a[Q][Q];
    float theta = 0.5f * (aqq - app) / apq;
    float t = 1.f / (fabsf(theta) + sqrtf(theta * theta + 1.f));
    t = (theta >= 0.f) ? t : -t;
    float c = rsqrtf(t * t + 1.f);
    float s = t * c;
    a[P][P] = app - t * apq;
    a[Q][Q] = aqq + t * apq;
    a[P][Q] = 0.f; a[Q][P] = 0.f;
    float arp = a[RR][P], arq = a[RR][Q];
    float nrp = c * arp - s * arq;
    float nrq = s * arp + c * arq;
    a[RR][P] = nrp; a[P][RR] = nrp;
    a[RR][Q] = nrq; a[Q][RR] = nrq;
#pragma unroll
    for (int r = 0; r < 3; ++r) {
      float vp = V[r][P], vq = V[r][Q];
      V[r][P] = c * vp - s * vq;
      V[r][Q] = s * vp + c * vq;
    }
  }
}

// Symmetric 3x3 matrix log via Jacobi eigendecomposition.
// s6 / L: order xx, yy, zz, xy, xz, yz. Eigenvalue floor 1e-6 (ref EPS).
__device__ inline void logm3(const float s6[6], float L[6]) {
  float a[3][3] = {{s6[0], s6[3], s6[4]},
                   {s6[3], s6[1], s6[5]},
                   {s6[4], s6[5], s6[2]}};
  float V[3][3] = {{1,0,0},{0,1,0},{0,0,1}};
#pragma unroll
  for (int sw = 0; sw < 6; ++sw) {
    jrot<0,1,2>(a, V);
    jrot<0,2,1>(a, V);
    jrot<1,2,0>(a, V);
  }
  float l0 = logf(fmaxf(a[0][0], 1e-6f));
  float l1 = logf(fmaxf(a[1][1], 1e-6f));
  float l2 = logf(fmaxf(a[2][2], 1e-6f));
  L[0] = l0*V[0][0]*V[0][0] + l1*V[0][1]*V[0][1] + l2*V[0][2]*V[0][2];
  L[1] = l0*V[1][0]*V[1][0] + l1*V[1][1]*V[1][1] + l2*V[1][2]*V[1][2];
  L[2] = l0*V[2][0]*V[2][0] + l1*V[2][1]*V[2][1] + l2*V[2][2]*V[2][2];
  L[3] = l0*V[0][0]*V[1][0] + l1*V[0][1]*V[1][1] + l2*V[0][2]*V[1][2];
  L[4] = l0*V[0][0]*V[2][0] + l1*V[0][1]*V[2][1] + l2*V[0][2]*V[2][2];
  L[5] = l0*V[1][0]*V[2][0] + l1*V[1][1]*V[2][1] + l2*V[1][2]*V[2][2];
}

__global__ void eigen_loss(const float* __restrict__ Sr, const float* __restrict__ Sf,
                           float* __restrict__ out) {
  int idx = blockIdx.x * TPB + threadIdx.x;
  float val = 0.f;
  if (idx < N3) {
    float sr[6], sf[6], Lr[6], Lf[6];
#pragma unroll
    for (int c = 0; c < 6; ++c) {
      sr[c] = Sr[c * N3 + idx];
      sf[c] = Sf[c * N3 + idx];
    }
    logm3(sr, Lr);
    logm3(sf, Lf);
    float d0 = Lr[0]-Lf[0], d1 = Lr[1]-Lf[1], d2 = Lr[2]-Lf[2];
    float d3 = Lr[3]-Lf[3], d4 = Lr[4]-Lf[4], d5 = Lr[5]-Lf[5];
    val = d0*d0 + d1*d1 + d2*d2 + 2.f*(d3*d3 + d4*d4 + d5*d5);
  }
  // wave reduce (64 lanes)
#pragma unroll
  for (int off = 32; off > 0; off >>= 1) val += __shfl_down(val, off, 64);
  __shared__ float sm[TPB / 64];
  int wave = threadIdx.x >> 6;
  if ((threadIdx.x & 63) == 0) sm[wave] = val;
  __syncthreads();
  if (threadIdx.x == 0) {
    float s = 0.f;
#pragma unroll
    for (int wv = 0; wv < TPB / 64; ++wv) s += sm[wv];
    atomicAdd(out, s * (1.0f / (float)N3));
  }
}

extern "C" void kernel_launch(void* const* d_in, const int* in_sizes, int n_in,
                              void* d_out, int out_size, void* d_ws, size_t ws_size,
                              hipStream_t stream) {
  const float* real = (const float*)d_in[0];
  const float* fake = (const float*)d_in[1];
  float* out = (float*)d_out;

  // Gaussian / derivative-of-Gaussian weights (computed host-side, f64 -> f32).
  CW<7> g7, d7;
  CW<13> g13;
  {
    double g[7], sum = 0.0;
    for (int i = 0; i < 7; ++i) { double t = i - 3; g[i] = exp(-0.5 * t * t); sum += g[i]; }
    for (int i = 0; i < 7; ++i) {
      double gn = g[i] / sum;
      g7.w[i] = (float)gn;
      d7.w[i] = (float)(-(double)(i - 3) * gn);   // sigma = 1
    }
    double h[13], s2 = 0.0;
    for (int i = 0; i < 13; ++i) { double t = (i - 6) / 2.0; h[i] = exp(-0.5 * t * t); s2 += h[i]; }
    for (int i = 0; i < 13; ++i) g13.w[i] = (float)(h[i] / s2);
  }

  // Workspace layout: R (6N real comps) | X (6N) | Y (6N)  => 18N floats ~= 61 MB
  float* R = (float*)d_ws;
  float* X = R + (size_t)6 * N3;
  float* Y = X + (size_t)6 * N3;

  hipMemsetAsync(d_out, 0, sizeof(float) * (size_t)out_size, stream);

  const int gN  = (N3 + TPB - 1) / TPB;       // 3456
  const int g6N = (6 * N3 + TPB - 1) / TPB;   // 20736

  for (int b = 0; b < 2; ++b) {
    for (int which = 0; which < 2; ++which) {
      const float* v = (which == 0 ? real : fake) + (size_t)b * N3;
      float* OUTC = (which == 0) ? R : Y;

      // A: conv along W -> X0 = convW(v,g), X1 = convW(v,dg)
      conv1d_dual<3,1><<<gN, TPB, 0, stream>>>(v, X, X + N3, N3, g7, d7);
      // B: conv along H -> Y0 = convH(X0,g), Y1 = convH(X0,dg), Y2 = convH(X1,g)
      conv1d_dual<3,DIM><<<gN, TPB, 0, stream>>>(X, Y, Y + N3, N3, g7, d7);
      conv1d<3,DIM><<<gN, TPB, 0, stream>>>(X + N3, Y + 2 * N3, N3, g7);
      // C: conv along D -> gx = X0 = convD(Y2,g), gy = X1 = convD(Y1,g), gz = X2 = convD(Y0,dg)
      conv1d<3,HW_><<<gN, TPB, 0, stream>>>(Y + 2 * N3, X, N3, g7);
      conv1d<3,HW_><<<gN, TPB, 0, stream>>>(Y + N3, X + N3, N3, g7);
      conv1d<3,HW_><<<gN, TPB, 0, stream>>>(Y, X + 2 * N3, N3, d7);
      // P1: products + 13-tap conv along W -> Y[0..5]
      prod_convW<<<gN, TPB, 0, stream>>>(X, X + N3, X + 2 * N3, Y, g13);
      // P2: 13-tap conv along H on all 6 comps -> X[0..5]
      conv1d<6,DIM><<<g6N, TPB, 0, stream>>>(Y, X, 6 * N3, g13);
      // P3: 13-tap conv along D on all 6 comps -> R (real) / Y (fake)
      conv1d<6,HW_><<<g6N, TPB, 0, stream>>>(X, OUTC, 6 * N3, g13);
    }
    // eigen + logm + Frobenius distance + reduction for this batch
    eigen_loss<<<gN, TPB, 0, stream>>>(R, Y, out);
  }
}

// Round 4
// 498.526 us; speedup vs baseline: 1.4498x; 1.4498x over previous
//
#include <hip/hip_runtime.h>
#include <math.h>

#define DIM 96
#define HW_ 9216               // 96*96
#define N3 884736              // 96^3
#define TPB 256

template<int K> struct CW { float w[K]; };

__device__ inline float4 ld4(const float* p) { return *reinterpret_cast<const float4*>(p); }
__device__ inline void st4(float* p, float4 v) { *reinterpret_cast<float4*>(p) = v; }
__device__ inline float4 fma4(float w, float4 a, float4 acc) {
  acc.x = fmaf(w, a.x, acc.x); acc.y = fmaf(w, a.y, acc.y);
  acc.z = fmaf(w, a.z, acc.z); acc.w = fmaf(w, a.w, acc.w); return acc;
}

// K1: dual 7-tap conv along W for two volumes (real_b, fake_b) -> A[4 fields]
// A layout: [Wg_r, Wdg_r, Wg_f, Wdg_f]
__global__ void k1_dualW(const float* __restrict__ rv, const float* __restrict__ fv,
                         float* __restrict__ A, CW<7> g, CW<7> dg) {
  int idx = blockIdx.x * TPB + threadIdx.x;
  if (idx >= 2 * N3) return;
  int v = idx / N3, i = idx - v * N3;
  const float* src = v ? fv : rv;
  int x = i % DIM;
  float sa = 0.f, sb = 0.f;
#pragma unroll
  for (int j = -3; j <= 3; ++j) {
    int xx = x + j;
    if (0 <= xx && xx < DIM) {
      float val = src[i + j];
      sa = fmaf(g.w[j + 3], val, sa);
      sb = fmaf(dg.w[j + 3], val, sb);
    }
  }
  A[(size_t)(2 * v) * N3 + i] = sa;
  A[(size_t)(2 * v + 1) * N3 + i] = sb;
}

// K2: 7-tap conv along H (float4). In: A[4F]. Out: B[6F] = [t0,t1,t2]_r, [t0,t1,t2]_f
// t0 = Hg(Wg) [->gz], t1 = Hdg(Wg) [->gy], t2 = Hg(Wdg) [->gx]
__global__ void k2_H(const float* __restrict__ A, float* __restrict__ B,
                     CW<7> g, CW<7> dg) {
  int t = blockIdx.x * TPB + threadIdx.x;
  if (t >= 2 * N3 / 4) return;
  int base = t * 4;
  int v = base / N3, i = base - v * N3;
  int h = (i / DIM) % DIM;
  const float* Wg  = A + (size_t)(2 * v) * N3;
  const float* Wdg = A + (size_t)(2 * v + 1) * N3;
  float4 t0 = {0,0,0,0}, t1 = {0,0,0,0}, t2 = {0,0,0,0};
#pragma unroll
  for (int j = -3; j <= 3; ++j) {
    int hh = h + j;
    if (0 <= hh && hh < DIM) {
      float4 a = ld4(Wg + i + j * DIM);
      t0 = fma4(g.w[j + 3], a, t0);
      t1 = fma4(dg.w[j + 3], a, t1);
      float4 b = ld4(Wdg + i + j * DIM);
      t2 = fma4(g.w[j + 3], b, t2);
    }
  }
  st4(B + (size_t)(3 * v + 0) * N3 + i, t0);
  st4(B + (size_t)(3 * v + 1) * N3 + i, t1);
  st4(B + (size_t)(3 * v + 2) * N3 + i, t2);
}

// K3: 7-tap conv along D (float4) on 6 fields; field f%3==0 (t0) uses dg, else g.
// Out A[f] : [gz, gy, gx]_r, [gz, gy, gx]_f
__global__ void k3_D(const float* __restrict__ B, float* __restrict__ A,
                     CW<7> g, CW<7> dg) {
  int t = blockIdx.x * TPB + threadIdx.x;
  if (t >= 6 * N3 / 4) return;
  int base = t * 4;
  int f = base / N3;
  int d = (base / HW_) % DIM;   // N3/HW_ == DIM so this is the in-field d
  bool use_dg = (f % 3 == 0);
  float4 acc = {0,0,0,0};
#pragma unroll
  for (int j = -3; j <= 3; ++j) {
    int dd = d + j;
    if (0 <= dd && dd < DIM) {
      float w = use_dg ? dg.w[j + 3] : g.w[j + 3];
      acc = fma4(w, ld4(B + base + j * HW_), acc);
    }
  }
  st4(A + base, acc);
}

// K4: gradient products + 13-tap blur along W. In A[6F] -> real comps into Br[6F],
// fake comps into Cf[6F]. Comp order: xx,yy,zz,xy,xz,yz.
__global__ void k4_prodW(const float* __restrict__ A, float* __restrict__ Br,
                         float* __restrict__ Cf, CW<13> w13) {
  int idx = blockIdx.x * TPB + threadIdx.x;
  if (idx >= 2 * N3) return;
  int v = idx / N3, i = idx - v * N3;
  const float* gz = A + (size_t)(3 * v + 0) * N3;
  const float* gy = A + (size_t)(3 * v + 1) * N3;
  const float* gx = A + (size_t)(3 * v + 2) * N3;
  int x = i % DIM;
  float a0=0.f,a1=0.f,a2=0.f,a3=0.f,a4=0.f,a5=0.f;
#pragma unroll
  for (int j = -6; j <= 6; ++j) {
    int xx = x + j;
    if (xx < 0 || xx >= DIM) continue;
    float w = w13.w[j + 6];
    float a = gx[i + j], b = gy[i + j], c = gz[i + j];
    a0 = fmaf(w * a, a, a0);  a1 = fmaf(w * b, b, a1);  a2 = fmaf(w * c, c, a2);
    a3 = fmaf(w * a, b, a3);  a4 = fmaf(w * a, c, a4);  a5 = fmaf(w * b, c, a5);
  }
  float* dst = v ? Cf : Br;
  dst[0*N3+i]=a0; dst[1*N3+i]=a1; dst[2*N3+i]=a2;
  dst[3*N3+i]=a3; dst[4*N3+i]=a4; dst[5*N3+i]=a5;
}

// K5: 13-tap blur along H on 6 fields (float4), In -> Out.
__global__ void k5_blurH(const float* __restrict__ In, float* __restrict__ Out,
                         CW<13> w13) {
  int t = blockIdx.x * TPB + threadIdx.x;
  if (t >= 6 * N3 / 4) return;
  int base = t * 4;
  int h = (base / DIM) % DIM;   // in-field h (N3 multiple of 96*96)
  float4 acc = {0,0,0,0};
#pragma unroll
  for (int j = -6; j <= 6; ++j) {
    int hh = h + j;
    if (0 <= hh && hh < DIM)
      acc = fma4(w13.w[j + 6], ld4(In + base + j * DIM), acc);
  }
  st4(Out + base, acc);
}

// ---- symmetric 3x3 matrix log (cyclic Jacobi, 4 sweeps) ----
template<int P, int Q, int RR>
__device__ inline void jrot(float a[3][3], float V[3][3]) {
  float apq = a[P][Q];
  if (apq != 0.f) {
    float app = a[P][P], aqq = a[Q][Q];
    float theta = 0.5f * (aqq - app) / apq;
    float t = 1.f / (fabsf(theta) + sqrtf(theta * theta + 1.f));
    t = (theta >= 0.f) ? t : -t;
    float c = rsqrtf(t * t + 1.f);
    float s = t * c;
    a[P][P] = app - t * apq;
    a[Q][Q] = aqq + t * apq;
    a[P][Q] = 0.f; a[Q][P] = 0.f;
    float arp = a[RR][P], arq = a[RR][Q];
    float nrp = c * arp - s * arq;
    float nrq = s * arp + c * arq;
    a[RR][P] = nrp; a[P][RR] = nrp;
    a[RR][Q] = nrq; a[Q][RR] = nrq;
#pragma unroll
    for (int r = 0; r < 3; ++r) {
      float vp = V[r][P], vq = V[r][Q];
      V[r][P] = c * vp - s * vq;
      V[r][Q] = s * vp + c * vq;
    }
  }
}

__device__ inline void logm3(const float s6[6], float L[6]) {
  float a[3][3] = {{s6[0], s6[3], s6[4]},
                   {s6[3], s6[1], s6[5]},
                   {s6[4], s6[5], s6[2]}};
  float V[3][3] = {{1,0,0},{0,1,0},{0,0,1}};
#pragma unroll
  for (int sw = 0; sw < 4; ++sw) {
    jrot<0,1,2>(a, V);
    jrot<0,2,1>(a, V);
    jrot<1,2,0>(a, V);
  }
  float l0 = logf(fmaxf(a[0][0], 1e-6f));
  float l1 = logf(fmaxf(a[1][1], 1e-6f));
  float l2 = logf(fmaxf(a[2][2], 1e-6f));
  L[0] = l0*V[0][0]*V[0][0] + l1*V[0][1]*V[0][1] + l2*V[0][2]*V[0][2];
  L[1] = l0*V[1][0]*V[1][0] + l1*V[1][1]*V[1][1] + l2*V[1][2]*V[1][2];
  L[2] = l0*V[2][0]*V[2][0] + l1*V[2][1]*V[2][1] + l2*V[2][2]*V[2][2];
  L[3] = l0*V[0][0]*V[1][0] + l1*V[0][1]*V[1][1] + l2*V[0][2]*V[1][2];
  L[4] = l0*V[0][0]*V[2][0] + l1*V[0][1]*V[2][1] + l2*V[0][2]*V[2][2];
  L[5] = l0*V[1][0]*V[2][0] + l1*V[1][1]*V[2][1] + l2*V[1][2]*V[2][2];
}

// K6a: 13-tap blur along D on 6 comps + logm -> store L (real volume).
__global__ void k6_logm_store(const float* __restrict__ S, float* __restrict__ L,
                              CW<13> w13) {
  int idx = blockIdx.x * TPB + threadIdx.x;
  if (idx >= N3) return;
  int d = idx / HW_;
  float s6[6];
#pragma unroll
  for (int c = 0; c < 6; ++c) {
    float acc = 0.f;
#pragma unroll
    for (int j = -6; j <= 6; ++j) {
      int dd = d + j;
      if (0 <= dd && dd < DIM)
        acc = fmaf(w13.w[j + 6], S[(size_t)c * N3 + idx + j * HW_], acc);
    }
    s6[c] = acc;
  }
  float Lv[6];
  logm3(s6, Lv);
#pragma unroll
  for (int c = 0; c < 6; ++c) L[(size_t)c * N3 + idx] = Lv[c];
}

// K6b: blur-D + logm for fake, diff vs stored L_real, reduce loss.
__global__ void k6_logm_loss(const float* __restrict__ S, const float* __restrict__ Lr,
                             float* __restrict__ out, CW<13> w13) {
  int idx = blockIdx.x * TPB + threadIdx.x;
  float val = 0.f;
  if (idx < N3) {
    int d = idx / HW_;
    float s6[6];
#pragma unroll
    for (int c = 0; c < 6; ++c) {
      float acc = 0.f;
#pragma unroll
      for (int j = -6; j <= 6; ++j) {
        int dd = d + j;
        if (0 <= dd && dd < DIM)
          acc = fmaf(w13.w[j + 6], S[(size_t)c * N3 + idx + j * HW_], acc);
      }
      s6[c] = acc;
    }
    float Lf[6];
    logm3(s6, Lf);
    float d0 = Lr[0*N3+idx]-Lf[0], d1 = Lr[1*N3+idx]-Lf[1], d2 = Lr[2*N3+idx]-Lf[2];
    float d3 = Lr[3*N3+idx]-Lf[3], d4 = Lr[4*N3+idx]-Lf[4], d5 = Lr[5*N3+idx]-Lf[5];
    val = d0*d0 + d1*d1 + d2*d2 + 2.f*(d3*d3 + d4*d4 + d5*d5);
  }
#pragma unroll
  for (int off = 32; off > 0; off >>= 1) val += __shfl_down(val, off, 64);
  __shared__ float sm[TPB / 64];
  int wave = threadIdx.x >> 6;
  if ((threadIdx.x & 63) == 0) sm[wave] = val;
  __syncthreads();
  if (threadIdx.x == 0) {
    float s = 0.f;
#pragma unroll
    for (int wv = 0; wv < TPB / 64; ++wv) s += sm[wv];
    atomicAdd(out, s * (1.0f / (float)N3));
  }
}

extern "C" void kernel_launch(void* const* d_in, const int* in_sizes, int n_in,
                              void* d_out, int out_size, void* d_ws, size_t ws_size,
                              hipStream_t stream) {
  const float* real = (const float*)d_in[0];
  const float* fake = (const float*)d_in[1];
  float* out = (float*)d_out;

  CW<7> g7, d7;
  CW<13> g13;
  {
    double g[7], sum = 0.0;
    for (int i = 0; i < 7; ++i) { double t = i - 3; g[i] = exp(-0.5 * t * t); sum += g[i]; }
    for (int i = 0; i < 7; ++i) {
      double gn = g[i] / sum;
      g7.w[i] = (float)gn;
      d7.w[i] = (float)(-(double)(i - 3) * gn);   // sigma = 1
    }
    double h[13], s2 = 0.0;
    for (int i = 0; i < 13; ++i) { double t = (i - 6) / 2.0; h[i] = exp(-0.5 * t * t); s2 += h[i]; }
    for (int i = 0; i < 13; ++i) g13.w[i] = (float)(h[i] / s2);
  }

  // Workspace: A|B|C, each 6 fields of N3 floats => 18 fields ~= 60.8 MiB (as before)
  float* A = (float*)d_ws;
  float* B = A + (size_t)6 * N3;
  float* C = B + (size_t)6 * N3;

  hipMemsetAsync(d_out, 0, sizeof(float) * (size_t)out_size, stream);

  const int g2N   = (2 * N3 + TPB - 1) / TPB;        // scalar, 2 vols
  const int g2N4  = (2 * N3 / 4 + TPB - 1) / TPB;    // float4, 2 vols
  const int g6N4  = (6 * N3 / 4 + TPB - 1) / TPB;    // float4, 6 fields
  const int gN    = (N3 + TPB - 1) / TPB;

  for (int b = 0; b < 2; ++b) {
    const float* rv = real + (size_t)b * N3;
    const float* fv = fake + (size_t)b * N3;
    // gradients (both volumes per pass)
    k1_dualW<<<g2N,  TPB, 0, stream>>>(rv, fv, A, g7, d7);       // v -> Wg, Wdg      (A:4F)
    k2_H    <<<g2N4, TPB, 0, stream>>>(A, B, g7, d7);            // -> t0,t1,t2       (B:6F)
    k3_D    <<<g6N4, TPB, 0, stream>>>(B, A, g7, d7);            // -> gz,gy,gx       (A:6F)
    // structure tensor comps + rho-blur
    k4_prodW<<<g2N,  TPB, 0, stream>>>(A, B, C, g13);            // -> S_w real(B) fake(C)
    k5_blurH<<<g6N4, TPB, 0, stream>>>(B, A, g13);               // real S_wh  -> A
    k5_blurH<<<g6N4, TPB, 0, stream>>>(C, B, g13);               // fake S_wh  -> B
    // blur-D + matrix log + loss
    k6_logm_store<<<gN, TPB, 0, stream>>>(A, C, g13);            // L_real -> C
    k6_logm_loss <<<gN, TPB, 0, stream>>>(B, C, out, g13);       // fake vs L_real
  }
}